// Round 1
// baseline (1428.513 us; speedup 1.0000x reference)
//
#include <hip/hip_runtime.h>

// Wilson Dslash, 32^4 lattice, DeGrand-Rossi basis, separate re/im fp32 planes.
// res(x) = -0.5 * sum_mu [ (I-g_mu) U_mu(x) psi(x+mu) + (I+g_mu) U_mu(x-mu)^dag psi(x-mu) ]
// Spin-projection trick: (I -+ g_mu) v is rank-2 -> project to 2 half-spinors h0,h1,
// color-multiply only those (halves the 3x3 complex matvec work), reconstruct lower
// spin rows from g0,g1 with the fixed phase per mu (derived & row-checked vs gamma defs).
//
// R1 changes vs 625us baseline (latency-bound: VALU 12.7%, HBM 39%, occ 11.7%, VGPR 212):
//  - __launch_bounds__(256, 3): cap VGPRs ~170 -> 3 waves/SIMD instead of 2 (+50% latency hiding)
//  - bijective XCD swizzle (4096 blocks = 8 XCDs x 512): each XCD owns 4 contiguous
//    x-slices; one x-slice of psi = 3.1 MB fits the 4 MB per-XCD L2, and the mu=1
//    backward-hop U(y-1) re-read becomes an L2 hit instead of a 2nd HBM fetch.

static constexpr int SITES = 32 * 32 * 32 * 32;

__device__ __forceinline__ void load12(const float* __restrict__ p, float* v) {
    const float4* q = reinterpret_cast<const float4*>(p);  // site*12 floats = 48B, 16B-aligned
    float4 a = q[0], b = q[1], c = q[2];
    v[0] = a.x; v[1] = a.y; v[2]  = a.z; v[3]  = a.w;
    v[4] = b.x; v[5] = b.y; v[6]  = b.z; v[7]  = b.w;
    v[8] = c.x; v[9] = c.y; v[10] = c.z; v[11] = c.w;
}

__global__ __launch_bounds__(256, 3) void wilson_dslash_kernel(
    const float* __restrict__ psi_re, const float* __restrict__ psi_im,
    const float* __restrict__ U_re,   const float* __restrict__ U_im,
    float* __restrict__ out_re,       float* __restrict__ out_im)
{
    // XCD-aware bijective swizzle: dispatcher round-robins blockIdx across the 8 XCDs,
    // so blocks with (blockIdx & 7) == c land on XCD c. Give XCD c the contiguous
    // chunk [c*512, (c+1)*512) of the site space -> spatially-adjacent blocks share
    // one (coherent) L2 instead of being scattered across 8 incoherent ones.
    const int blk  = ((blockIdx.x & 7) << 9) | (blockIdx.x >> 3);  // 4096 = 8 * 512, bijective
    const int site = blk * 256 + threadIdx.x;
    const int t =  site        & 31;
    const int z = (site >> 5)  & 31;
    const int y = (site >> 10) & 31;
    const int x = (site >> 15) & 31;

    float ar[12], ai[12];   // accumulator, index = spin*3 + color
#pragma unroll
    for (int k = 0; k < 12; ++k) { ar[k] = 0.f; ai[k] = 0.f; }

    const int coord[4]  = {x, y, z, t};
    const int stride[4] = {32768, 1024, 32, 1};

#pragma unroll
    for (int mu = 0; mu < 4; ++mu) {
        const int cmu = coord[mu];
        const int S   = stride[mu];
        const int nf  = site + (cmu == 31 ? -31 * S : S);   // x + mu (periodic)
        const int nb  = site + (cmu == 0  ?  31 * S : -S);  // x - mu (periodic)

        float vr[12], vi[12];
        float hr[6], hi[6];   // half-spinor, index = s*3 + color, s in {0,1}
        float gr[6], gi[6];
        float ur[9], ui[9];

        // ================= forward hop: (I - g_mu) U_mu(x) psi(x+mu) =================
        load12(psi_re + nf * 12, vr);
        load12(psi_im + nf * 12, vi);
#pragma unroll
        for (int c = 0; c < 3; ++c) {
            if (mu == 0) {          // h0 = v0 - i v3 ; h1 = v1 - i v2
                hr[c]     = vr[c]     + vi[9 + c];  hi[c]     = vi[c]     - vr[9 + c];
                hr[3 + c] = vr[3 + c] + vi[6 + c];  hi[3 + c] = vi[3 + c] - vr[6 + c];
            } else if (mu == 1) {   // h0 = v0 + v3 ; h1 = v1 - v2
                hr[c]     = vr[c]     + vr[9 + c];  hi[c]     = vi[c]     + vi[9 + c];
                hr[3 + c] = vr[3 + c] - vr[6 + c];  hi[3 + c] = vi[3 + c] - vi[6 + c];
            } else if (mu == 2) {   // h0 = v0 - i v2 ; h1 = v1 + i v3
                hr[c]     = vr[c]     + vi[6 + c];  hi[c]     = vi[c]     - vr[6 + c];
                hr[3 + c] = vr[3 + c] - vi[9 + c];  hi[3 + c] = vi[3 + c] + vr[9 + c];
            } else {                // h0 = v0 - v2 ; h1 = v1 - v3
                hr[c]     = vr[c]     - vr[6 + c];  hi[c]     = vi[c]     - vi[6 + c];
                hr[3 + c] = vr[3 + c] - vr[9 + c];  hi[3 + c] = vi[3 + c] - vi[9 + c];
            }
        }
        {
            const float* pur = U_re + (site * 4 + mu) * 9;
            const float* pui = U_im + (site * 4 + mu) * 9;
#pragma unroll
            for (int k = 0; k < 9; ++k) { ur[k] = pur[k]; ui[k] = pui[k]; }
        }
        // g[s][i] = sum_j U[i][j] h[s][j]   (complex)
#pragma unroll
        for (int s = 0; s < 2; ++s)
#pragma unroll
            for (int i = 0; i < 3; ++i) {
                float rr = 0.f, im = 0.f;
#pragma unroll
                for (int j = 0; j < 3; ++j) {
                    rr += ur[i * 3 + j] * hr[s * 3 + j] - ui[i * 3 + j] * hi[s * 3 + j];
                    im += ur[i * 3 + j] * hi[s * 3 + j] + ui[i * 3 + j] * hr[s * 3 + j];
                }
                gr[s * 3 + i] = rr; gi[s * 3 + i] = im;
            }
        // reconstruct: rows 0,1 += g0,g1 always; rows 2,3 per mu
#pragma unroll
        for (int c = 0; c < 3; ++c) {
            ar[c]     += gr[c];      ai[c]     += gi[c];
            ar[3 + c] += gr[3 + c];  ai[3 + c] += gi[3 + c];
            if (mu == 0) {          // r2 += i g1 ; r3 += i g0
                ar[6 + c] -= gi[3 + c];  ai[6 + c] += gr[3 + c];
                ar[9 + c] -= gi[c];      ai[9 + c] += gr[c];
            } else if (mu == 1) {   // r2 += -g1 ; r3 += g0
                ar[6 + c] -= gr[3 + c];  ai[6 + c] -= gi[3 + c];
                ar[9 + c] += gr[c];      ai[9 + c] += gi[c];
            } else if (mu == 2) {   // r2 += i g0 ; r3 += -i g1
                ar[6 + c] -= gi[c];      ai[6 + c] += gr[c];
                ar[9 + c] += gi[3 + c];  ai[9 + c] -= gr[3 + c];
            } else {                // r2 += -g0 ; r3 += -g1
                ar[6 + c] -= gr[c];      ai[6 + c] -= gi[c];
                ar[9 + c] -= gr[3 + c];  ai[9 + c] -= gi[3 + c];
            }
        }

        // ================= backward hop: (I + g_mu) U_mu(x-mu)^dag psi(x-mu) =================
        load12(psi_re + nb * 12, vr);
        load12(psi_im + nb * 12, vi);
#pragma unroll
        for (int c = 0; c < 3; ++c) {
            if (mu == 0) {          // h0 = v0 + i v3 ; h1 = v1 + i v2
                hr[c]     = vr[c]     - vi[9 + c];  hi[c]     = vi[c]     + vr[9 + c];
                hr[3 + c] = vr[3 + c] - vi[6 + c];  hi[3 + c] = vi[3 + c] + vr[6 + c];
            } else if (mu == 1) {   // h0 = v0 - v3 ; h1 = v1 + v2
                hr[c]     = vr[c]     - vr[9 + c];  hi[c]     = vi[c]     - vi[9 + c];
                hr[3 + c] = vr[3 + c] + vr[6 + c];  hi[3 + c] = vi[3 + c] + vi[6 + c];
            } else if (mu == 2) {   // h0 = v0 + i v2 ; h1 = v1 - i v3
                hr[c]     = vr[c]     - vi[6 + c];  hi[c]     = vi[c]     + vr[6 + c];
                hr[3 + c] = vr[3 + c] + vi[9 + c];  hi[3 + c] = vi[3 + c] - vr[9 + c];
            } else {                // h0 = v0 + v2 ; h1 = v1 + v3
                hr[c]     = vr[c]     + vr[6 + c];  hi[c]     = vi[c]     + vi[6 + c];
                hr[3 + c] = vr[3 + c] + vr[9 + c];  hi[3 + c] = vi[3 + c] + vi[9 + c];
            }
        }
        {
            const float* pur = U_re + (nb * 4 + mu) * 9;
            const float* pui = U_im + (nb * 4 + mu) * 9;
#pragma unroll
            for (int k = 0; k < 9; ++k) { ur[k] = pur[k]; ui[k] = pui[k]; }
        }
        // g[s][i] = sum_j conj(U[j][i]) h[s][j]
#pragma unroll
        for (int s = 0; s < 2; ++s)
#pragma unroll
            for (int i = 0; i < 3; ++i) {
                float rr = 0.f, im = 0.f;
#pragma unroll
                for (int j = 0; j < 3; ++j) {
                    rr += ur[j * 3 + i] * hr[s * 3 + j] + ui[j * 3 + i] * hi[s * 3 + j];
                    im += ur[j * 3 + i] * hi[s * 3 + j] - ui[j * 3 + i] * hr[s * 3 + j];
                }
                gr[s * 3 + i] = rr; gi[s * 3 + i] = im;
            }
#pragma unroll
        for (int c = 0; c < 3; ++c) {
            ar[c]     += gr[c];      ai[c]     += gi[c];
            ar[3 + c] += gr[3 + c];  ai[3 + c] += gi[3 + c];
            if (mu == 0) {          // r2 += -i g1 ; r3 += -i g0
                ar[6 + c] += gi[3 + c];  ai[6 + c] -= gr[3 + c];
                ar[9 + c] += gi[c];      ai[9 + c] -= gr[c];
            } else if (mu == 1) {   // r2 += g1 ; r3 += -g0
                ar[6 + c] += gr[3 + c];  ai[6 + c] += gi[3 + c];
                ar[9 + c] -= gr[c];      ai[9 + c] -= gi[c];
            } else if (mu == 2) {   // r2 += -i g0 ; r3 += i g1
                ar[6 + c] += gi[c];      ai[6 + c] -= gr[c];
                ar[9 + c] -= gi[3 + c];  ai[9 + c] += gr[3 + c];
            } else {                // r2 += g0 ; r3 += g1
                ar[6 + c] += gr[c];      ai[6 + c] += gi[c];
                ar[9 + c] += gr[3 + c];  ai[9 + c] += gi[3 + c];
            }
        }
    }

    // out = -0.5 * acc, vectorized stores
    float4* orp = reinterpret_cast<float4*>(out_re + site * 12);
    float4* oip = reinterpret_cast<float4*>(out_im + site * 12);
    orp[0] = make_float4(-0.5f * ar[0], -0.5f * ar[1], -0.5f * ar[2],  -0.5f * ar[3]);
    orp[1] = make_float4(-0.5f * ar[4], -0.5f * ar[5], -0.5f * ar[6],  -0.5f * ar[7]);
    orp[2] = make_float4(-0.5f * ar[8], -0.5f * ar[9], -0.5f * ar[10], -0.5f * ar[11]);
    oip[0] = make_float4(-0.5f * ai[0], -0.5f * ai[1], -0.5f * ai[2],  -0.5f * ai[3]);
    oip[1] = make_float4(-0.5f * ai[4], -0.5f * ai[5], -0.5f * ai[6],  -0.5f * ai[7]);
    oip[2] = make_float4(-0.5f * ai[8], -0.5f * ai[9], -0.5f * ai[10], -0.5f * ai[11]);
}

extern "C" void kernel_launch(void* const* d_in, const int* in_sizes, int n_in,
                              void* d_out, int out_size, void* d_ws, size_t ws_size,
                              hipStream_t stream) {
    const float* psi_re = (const float*)d_in[0];
    const float* psi_im = (const float*)d_in[1];
    const float* U_re   = (const float*)d_in[2];
    const float* U_im   = (const float*)d_in[3];
    // d_in[4..7] are the projector matrices; hardcoded in-kernel.
    float* out_re = (float*)d_out;
    float* out_im = out_re + (size_t)SITES * 12;

    wilson_dslash_kernel<<<SITES / 256, 256, 0, stream>>>(
        psi_re, psi_im, U_re, U_im, out_re, out_im);
}

// Round 2
// 643.872 us; speedup vs baseline: 2.2186x; 2.2186x over previous
//
#include <hip/hip_runtime.h>

// Wilson Dslash, 32^4 lattice, DeGrand-Rossi basis, separate re/im fp32 planes.
// res(x) = -0.5 * sum_mu [ (I-g_mu) U_mu(x) psi(x+mu) + (I+g_mu) U_mu(x-mu)^dag psi(x-mu) ]
// Spin-projection trick: (I -+ g_mu) v is rank-2 -> project to 2 half-spinors h0,h1,
// color-multiply only those, reconstruct lower spin rows with fixed per-mu phases.
//
// R2: R1's __launch_bounds__(256,3) on the fully-unrolled body made the allocator
// jump to 84 VGPR + massive scratch spills (WRITE_SIZE 98MB->1.76GB). Fix the
// pressure STRUCTURALLY instead:
//  - mu-loop NOT unrolled (#pragma unroll 1): one iteration's live set is ~100
//    floats, so the compiler can't inflate to 212 regs prefetching across hops.
//  - __launch_bounds__(256, 4): cap at 128 VGPR == an occupancy quantization step
//    (waves/SIMD halve at 64/128/256), giving 4 waves/SIMD vs baseline's 2.
//  - keep bijective XCD swizzle (4096 = 8 x 512) for per-XCD L2 locality.
// mu is a uniform loop counter -> all if(mu==k) chains are s_cbranch, no divergence.

static constexpr int SITES = 32 * 32 * 32 * 32;

__device__ __forceinline__ void load12(const float* __restrict__ p, float* v) {
    const float4* q = reinterpret_cast<const float4*>(p);  // site*12 floats = 48B, 16B-aligned
    float4 a = q[0], b = q[1], c = q[2];
    v[0] = a.x; v[1] = a.y; v[2]  = a.z; v[3]  = a.w;
    v[4] = b.x; v[5] = b.y; v[6]  = b.z; v[7]  = b.w;
    v[8] = c.x; v[9] = c.y; v[10] = c.z; v[11] = c.w;
}

__global__ __launch_bounds__(256, 4) void wilson_dslash_kernel(
    const float* __restrict__ psi_re, const float* __restrict__ psi_im,
    const float* __restrict__ U_re,   const float* __restrict__ U_im,
    float* __restrict__ out_re,       float* __restrict__ out_im)
{
    // XCD-aware bijective swizzle: blocks with (blockIdx & 7)==c land on XCD c;
    // give XCD c the contiguous chunk [c*512,(c+1)*512) of site space.
    const int blk  = ((blockIdx.x & 7) << 9) | (blockIdx.x >> 3);  // 4096 = 8 * 512
    const int site = blk * 256 + threadIdx.x;

    float ar[12], ai[12];   // accumulator, index = spin*3 + color
#pragma unroll
    for (int k = 0; k < 12; ++k) { ar[k] = 0.f; ai[k] = 0.f; }

#pragma unroll 1
    for (int mu = 0; mu < 4; ++mu) {
        const int sh  = 15 - 5 * mu;          // stride = 2^sh: x=15, y=10, z=5, t=0
        const int S   = 1 << sh;
        const int cmu = (site >> sh) & 31;
        const int nf  = site + (cmu == 31 ? -31 * S : S);   // x + mu (periodic)
        const int nb  = site + (cmu == 0  ?  31 * S : -S);  // x - mu (periodic)

        float vr[12], vi[12];
        float hr[6], hi[6];   // half-spinor, index = s*3 + color
        float gr[6], gi[6];
        float ur[9], ui[9];

        // ================= forward hop: (I - g_mu) U_mu(x) psi(x+mu) =================
        load12(psi_re + nf * 12, vr);
        load12(psi_im + nf * 12, vi);
        {
            const float* pur = U_re + (site * 4 + mu) * 9;
            const float* pui = U_im + (site * 4 + mu) * 9;
#pragma unroll
            for (int k = 0; k < 9; ++k) { ur[k] = pur[k]; ui[k] = pui[k]; }
        }
        if (mu == 0) {          // h0 = v0 - i v3 ; h1 = v1 - i v2
#pragma unroll
            for (int c = 0; c < 3; ++c) {
                hr[c]     = vr[c]     + vi[9 + c];  hi[c]     = vi[c]     - vr[9 + c];
                hr[3 + c] = vr[3 + c] + vi[6 + c];  hi[3 + c] = vi[3 + c] - vr[6 + c];
            }
        } else if (mu == 1) {   // h0 = v0 + v3 ; h1 = v1 - v2
#pragma unroll
            for (int c = 0; c < 3; ++c) {
                hr[c]     = vr[c]     + vr[9 + c];  hi[c]     = vi[c]     + vi[9 + c];
                hr[3 + c] = vr[3 + c] - vr[6 + c];  hi[3 + c] = vi[3 + c] - vi[6 + c];
            }
        } else if (mu == 2) {   // h0 = v0 - i v2 ; h1 = v1 + i v3
#pragma unroll
            for (int c = 0; c < 3; ++c) {
                hr[c]     = vr[c]     + vi[6 + c];  hi[c]     = vi[c]     - vr[6 + c];
                hr[3 + c] = vr[3 + c] - vi[9 + c];  hi[3 + c] = vi[3 + c] + vr[9 + c];
            }
        } else {                // h0 = v0 - v2 ; h1 = v1 - v3
#pragma unroll
            for (int c = 0; c < 3; ++c) {
                hr[c]     = vr[c]     - vr[6 + c];  hi[c]     = vi[c]     - vi[6 + c];
                hr[3 + c] = vr[3 + c] - vr[9 + c];  hi[3 + c] = vi[3 + c] - vi[9 + c];
            }
        }
        // g[s][i] = sum_j U[i][j] h[s][j]   (complex)
#pragma unroll
        for (int s = 0; s < 2; ++s)
#pragma unroll
            for (int i = 0; i < 3; ++i) {
                float rr = 0.f, im = 0.f;
#pragma unroll
                for (int j = 0; j < 3; ++j) {
                    rr += ur[i * 3 + j] * hr[s * 3 + j] - ui[i * 3 + j] * hi[s * 3 + j];
                    im += ur[i * 3 + j] * hi[s * 3 + j] + ui[i * 3 + j] * hr[s * 3 + j];
                }
                gr[s * 3 + i] = rr; gi[s * 3 + i] = im;
            }
        // reconstruct: rows 0,1 += g0,g1 always; rows 2,3 per mu
#pragma unroll
        for (int c = 0; c < 3; ++c) {
            ar[c]     += gr[c];      ai[c]     += gi[c];
            ar[3 + c] += gr[3 + c];  ai[3 + c] += gi[3 + c];
        }
        if (mu == 0) {          // r2 += i g1 ; r3 += i g0
#pragma unroll
            for (int c = 0; c < 3; ++c) {
                ar[6 + c] -= gi[3 + c];  ai[6 + c] += gr[3 + c];
                ar[9 + c] -= gi[c];      ai[9 + c] += gr[c];
            }
        } else if (mu == 1) {   // r2 += -g1 ; r3 += g0
#pragma unroll
            for (int c = 0; c < 3; ++c) {
                ar[6 + c] -= gr[3 + c];  ai[6 + c] -= gi[3 + c];
                ar[9 + c] += gr[c];      ai[9 + c] += gi[c];
            }
        } else if (mu == 2) {   // r2 += i g0 ; r3 += -i g1
#pragma unroll
            for (int c = 0; c < 3; ++c) {
                ar[6 + c] -= gi[c];      ai[6 + c] += gr[c];
                ar[9 + c] += gi[3 + c];  ai[9 + c] -= gr[3 + c];
            }
        } else {                // r2 += -g0 ; r3 += -g1
#pragma unroll
            for (int c = 0; c < 3; ++c) {
                ar[6 + c] -= gr[c];      ai[6 + c] -= gi[c];
                ar[9 + c] -= gr[3 + c];  ai[9 + c] -= gi[3 + c];
            }
        }

        // ================= backward hop: (I + g_mu) U_mu(x-mu)^dag psi(x-mu) =================
        load12(psi_re + nb * 12, vr);
        load12(psi_im + nb * 12, vi);
        {
            const float* pur = U_re + (nb * 4 + mu) * 9;
            const float* pui = U_im + (nb * 4 + mu) * 9;
#pragma unroll
            for (int k = 0; k < 9; ++k) { ur[k] = pur[k]; ui[k] = pui[k]; }
        }
        if (mu == 0) {          // h0 = v0 + i v3 ; h1 = v1 + i v2
#pragma unroll
            for (int c = 0; c < 3; ++c) {
                hr[c]     = vr[c]     - vi[9 + c];  hi[c]     = vi[c]     + vr[9 + c];
                hr[3 + c] = vr[3 + c] - vi[6 + c];  hi[3 + c] = vi[3 + c] + vr[6 + c];
            }
        } else if (mu == 1) {   // h0 = v0 - v3 ; h1 = v1 + v2
#pragma unroll
            for (int c = 0; c < 3; ++c) {
                hr[c]     = vr[c]     - vr[9 + c];  hi[c]     = vi[c]     - vi[9 + c];
                hr[3 + c] = vr[3 + c] + vr[6 + c];  hi[3 + c] = vi[3 + c] + vi[6 + c];
            }
        } else if (mu == 2) {   // h0 = v0 + i v2 ; h1 = v1 - i v3
#pragma unroll
            for (int c = 0; c < 3; ++c) {
                hr[c]     = vr[c]     - vi[6 + c];  hi[c]     = vi[c]     + vr[6 + c];
                hr[3 + c] = vr[3 + c] + vi[9 + c];  hi[3 + c] = vi[3 + c] - vr[9 + c];
            }
        } else {                // h0 = v0 + v2 ; h1 = v1 + v3
#pragma unroll
            for (int c = 0; c < 3; ++c) {
                hr[c]     = vr[c]     + vr[6 + c];  hi[c]     = vi[c]     + vi[6 + c];
                hr[3 + c] = vr[3 + c] + vr[9 + c];  hi[3 + c] = vi[3 + c] + vi[9 + c];
            }
        }
        // g[s][i] = sum_j conj(U[j][i]) h[s][j]
#pragma unroll
        for (int s = 0; s < 2; ++s)
#pragma unroll
            for (int i = 0; i < 3; ++i) {
                float rr = 0.f, im = 0.f;
#pragma unroll
                for (int j = 0; j < 3; ++j) {
                    rr += ur[j * 3 + i] * hr[s * 3 + j] + ui[j * 3 + i] * hi[s * 3 + j];
                    im += ur[j * 3 + i] * hi[s * 3 + j] - ui[j * 3 + i] * hr[s * 3 + j];
                }
                gr[s * 3 + i] = rr; gi[s * 3 + i] = im;
            }
#pragma unroll
        for (int c = 0; c < 3; ++c) {
            ar[c]     += gr[c];      ai[c]     += gi[c];
            ar[3 + c] += gr[3 + c];  ai[3 + c] += gi[3 + c];
        }
        if (mu == 0) {          // r2 += -i g1 ; r3 += -i g0
#pragma unroll
            for (int c = 0; c < 3; ++c) {
                ar[6 + c] += gi[3 + c];  ai[6 + c] -= gr[3 + c];
                ar[9 + c] += gi[c];      ai[9 + c] -= gr[c];
            }
        } else if (mu == 1) {   // r2 += g1 ; r3 += -g0
#pragma unroll
            for (int c = 0; c < 3; ++c) {
                ar[6 + c] += gr[3 + c];  ai[6 + c] += gi[3 + c];
                ar[9 + c] -= gr[c];      ai[9 + c] -= gi[c];
            }
        } else if (mu == 2) {   // r2 += -i g0 ; r3 += i g1
#pragma unroll
            for (int c = 0; c < 3; ++c) {
                ar[6 + c] += gi[c];      ai[6 + c] -= gr[c];
                ar[9 + c] -= gi[3 + c];  ai[9 + c] += gr[3 + c];
            }
        } else {                // r2 += g0 ; r3 += g1
#pragma unroll
            for (int c = 0; c < 3; ++c) {
                ar[6 + c] += gr[c];      ai[6 + c] += gi[c];
                ar[9 + c] += gr[3 + c];  ai[9 + c] += gi[3 + c];
            }
        }
    }

    // out = -0.5 * acc, vectorized stores
    float4* orp = reinterpret_cast<float4*>(out_re + site * 12);
    float4* oip = reinterpret_cast<float4*>(out_im + site * 12);
    orp[0] = make_float4(-0.5f * ar[0], -0.5f * ar[1], -0.5f * ar[2],  -0.5f * ar[3]);
    orp[1] = make_float4(-0.5f * ar[4], -0.5f * ar[5], -0.5f * ar[6],  -0.5f * ar[7]);
    orp[2] = make_float4(-0.5f * ar[8], -0.5f * ar[9], -0.5f * ar[10], -0.5f * ar[11]);
    oip[0] = make_float4(-0.5f * ai[0], -0.5f * ai[1], -0.5f * ai[2],  -0.5f * ai[3]);
    oip[1] = make_float4(-0.5f * ai[4], -0.5f * ai[5], -0.5f * ai[6],  -0.5f * ai[7]);
    oip[2] = make_float4(-0.5f * ai[8], -0.5f * ai[9], -0.5f * ai[10], -0.5f * ai[11]);
}

extern "C" void kernel_launch(void* const* d_in, const int* in_sizes, int n_in,
                              void* d_out, int out_size, void* d_ws, size_t ws_size,
                              hipStream_t stream) {
    const float* psi_re = (const float*)d_in[0];
    const float* psi_im = (const float*)d_in[1];
    const float* U_re   = (const float*)d_in[2];
    const float* U_im   = (const float*)d_in[3];
    // d_in[4..7] are the projector matrices; hardcoded in-kernel.
    float* out_re = (float*)d_out;
    float* out_im = out_re + (size_t)SITES * 12;

    wilson_dslash_kernel<<<SITES / 256, 256, 0, stream>>>(
        psi_re, psi_im, U_re, U_im, out_re, out_im);
}

// Round 3
// 538.038 us; speedup vs baseline: 2.6550x; 1.1967x over previous
//
#include <hip/hip_runtime.h>

// Wilson Dslash, 32^4 lattice, DeGrand-Rossi basis, separate re/im fp32 planes.
// res(x) = -0.5 * sum_mu [ (I-g_mu) U_mu(x) psi(x+mu) + (I+g_mu) U_mu(x-mu)^dag psi(x-mu) ]
// Spin-projection trick: project to 2 half-spinors, color-multiply only those,
// reconstruct lower spin rows with fixed per-mu phases.
//
// R3: R2 (rolled mu loop) raised FETCH 1.02->1.26 GB: U records (144B/plane, 4 mu-
// chunks of 36B) were consumed one chunk per phase, lines evicted between phases ->
// each record fetched ~2-3x. Fix: stage each thread's own forward-U record in LDS
// at kernel entry (18 contiguous float4 loads -> one full-line fetch per record),
// then per phase read the mu-chunk back from LDS (runtime mu index is legal in LDS,
// unlike registers). No __syncthreads needed: threads read only their own slot.
// Backward-U chunk loads stay global: they alias a neighbor's staged record ->
// L1/L2/L3 hits, not HBM. Block=128 -> 38.9KB static LDS, 4 blocks/CU.

static constexpr int SITES = 32 * 32 * 32 * 32;

__device__ __forceinline__ void load12(const float* __restrict__ p, float* v) {
    const float4* q = reinterpret_cast<const float4*>(p);  // site*12 floats = 48B, 16B-aligned
    float4 a = q[0], b = q[1], c = q[2];
    v[0] = a.x; v[1] = a.y; v[2]  = a.z; v[3]  = a.w;
    v[4] = b.x; v[5] = b.y; v[6]  = b.z; v[7]  = b.w;
    v[8] = c.x; v[9] = c.y; v[10] = c.z; v[11] = c.w;
}

__global__ __launch_bounds__(128) void wilson_dslash_kernel(
    const float* __restrict__ psi_re, const float* __restrict__ psi_im,
    const float* __restrict__ U_re,   const float* __restrict__ U_im,
    float* __restrict__ out_re,       float* __restrict__ out_im)
{
    // XCD-aware bijective swizzle: 8192 blocks = 8 XCDs x 1024; XCD c owns the
    // contiguous chunk [c*1024,(c+1)*1024) of site space for L2 locality.
    const int blk  = ((blockIdx.x & 7) << 10) | (blockIdx.x >> 3);
    const int tid  = threadIdx.x;
    const int site = blk * 128 + tid;

    // Per-thread LDS slot: [re 36][pad 4][im 36] dwords, stride 76 (304B, 16B-aligned).
    __shared__ float uf[128 * 76];
    float* myu = &uf[tid * 76];
    {
        const float4* pr = reinterpret_cast<const float4*>(U_re + (size_t)site * 36);
        const float4* pi = reinterpret_cast<const float4*>(U_im + (size_t)site * 36);
        float4* dr = reinterpret_cast<float4*>(myu);        // tid*304B, 16B-aligned
        float4* di = reinterpret_cast<float4*>(myu + 40);   // +160B, 16B-aligned
#pragma unroll
        for (int k = 0; k < 9; ++k) { dr[k] = pr[k]; di[k] = pi[k]; }
    }

    float ar[12], ai[12];   // accumulator, index = spin*3 + color
#pragma unroll
    for (int k = 0; k < 12; ++k) { ar[k] = 0.f; ai[k] = 0.f; }

#pragma unroll 1
    for (int mu = 0; mu < 4; ++mu) {
        const int sh  = 15 - 5 * mu;          // stride = 2^sh: x=15, y=10, z=5, t=0
        const int S   = 1 << sh;
        const int cmu = (site >> sh) & 31;
        const int nf  = site + (cmu == 31 ? -31 * S : S);   // x + mu (periodic)
        const int nb  = site + (cmu == 0  ?  31 * S : -S);  // x - mu (periodic)

        float vr[12], vi[12];
        float hr[6], hi[6];   // half-spinor, index = s*3 + color
        float gr[6], gi[6];

        // ================= forward hop: (I - g_mu) U_mu(x) psi(x+mu) =================
        load12(psi_re + (size_t)nf * 12, vr);
        load12(psi_im + (size_t)nf * 12, vi);
        const float* urp = myu + mu * 9;        // LDS, dynamic mu index OK
        const float* uip = myu + 40 + mu * 9;
        if (mu == 0) {          // h0 = v0 - i v3 ; h1 = v1 - i v2
#pragma unroll
            for (int c = 0; c < 3; ++c) {
                hr[c]     = vr[c]     + vi[9 + c];  hi[c]     = vi[c]     - vr[9 + c];
                hr[3 + c] = vr[3 + c] + vi[6 + c];  hi[3 + c] = vi[3 + c] - vr[6 + c];
            }
        } else if (mu == 1) {   // h0 = v0 + v3 ; h1 = v1 - v2
#pragma unroll
            for (int c = 0; c < 3; ++c) {
                hr[c]     = vr[c]     + vr[9 + c];  hi[c]     = vi[c]     + vi[9 + c];
                hr[3 + c] = vr[3 + c] - vr[6 + c];  hi[3 + c] = vi[3 + c] - vi[6 + c];
            }
        } else if (mu == 2) {   // h0 = v0 - i v2 ; h1 = v1 + i v3
#pragma unroll
            for (int c = 0; c < 3; ++c) {
                hr[c]     = vr[c]     + vi[6 + c];  hi[c]     = vi[c]     - vr[6 + c];
                hr[3 + c] = vr[3 + c] - vi[9 + c];  hi[3 + c] = vi[3 + c] + vr[9 + c];
            }
        } else {                // h0 = v0 - v2 ; h1 = v1 - v3
#pragma unroll
            for (int c = 0; c < 3; ++c) {
                hr[c]     = vr[c]     - vr[6 + c];  hi[c]     = vi[c]     - vi[6 + c];
                hr[3 + c] = vr[3 + c] - vr[9 + c];  hi[3 + c] = vi[3 + c] - vi[9 + c];
            }
        }
        // g[s][i] = sum_j U[i][j] h[s][j]   (complex), U from LDS
#pragma unroll
        for (int s = 0; s < 2; ++s)
#pragma unroll
            for (int i = 0; i < 3; ++i) {
                float rr = 0.f, im = 0.f;
#pragma unroll
                for (int j = 0; j < 3; ++j) {
                    const float a = urp[i * 3 + j], b = uip[i * 3 + j];
                    rr += a * hr[s * 3 + j] - b * hi[s * 3 + j];
                    im += a * hi[s * 3 + j] + b * hr[s * 3 + j];
                }
                gr[s * 3 + i] = rr; gi[s * 3 + i] = im;
            }
        // reconstruct: rows 0,1 += g0,g1 always; rows 2,3 per mu
#pragma unroll
        for (int c = 0; c < 3; ++c) {
            ar[c]     += gr[c];      ai[c]     += gi[c];
            ar[3 + c] += gr[3 + c];  ai[3 + c] += gi[3 + c];
        }
        if (mu == 0) {          // r2 += i g1 ; r3 += i g0
#pragma unroll
            for (int c = 0; c < 3; ++c) {
                ar[6 + c] -= gi[3 + c];  ai[6 + c] += gr[3 + c];
                ar[9 + c] -= gi[c];      ai[9 + c] += gr[c];
            }
        } else if (mu == 1) {   // r2 += -g1 ; r3 += g0
#pragma unroll
            for (int c = 0; c < 3; ++c) {
                ar[6 + c] -= gr[3 + c];  ai[6 + c] -= gi[3 + c];
                ar[9 + c] += gr[c];      ai[9 + c] += gi[c];
            }
        } else if (mu == 2) {   // r2 += i g0 ; r3 += -i g1
#pragma unroll
            for (int c = 0; c < 3; ++c) {
                ar[6 + c] -= gi[c];      ai[6 + c] += gr[c];
                ar[9 + c] += gi[3 + c];  ai[9 + c] -= gr[3 + c];
            }
        } else {                // r2 += -g0 ; r3 += -g1
#pragma unroll
            for (int c = 0; c < 3; ++c) {
                ar[6 + c] -= gr[c];      ai[6 + c] -= gi[c];
                ar[9 + c] -= gr[3 + c];  ai[9 + c] -= gi[3 + c];
            }
        }

        // ================= backward hop: (I + g_mu) U_mu(x-mu)^dag psi(x-mu) =================
        load12(psi_re + (size_t)nb * 12, vr);
        load12(psi_im + (size_t)nb * 12, vi);
        float ur[9], ui[9];
        {
            // Aliases the neighbor's staged record -> L1/L2/L3 hit, not HBM.
            const float* pur = U_re + ((size_t)nb * 4 + mu) * 9;
            const float* pui = U_im + ((size_t)nb * 4 + mu) * 9;
#pragma unroll
            for (int k = 0; k < 9; ++k) { ur[k] = pur[k]; ui[k] = pui[k]; }
        }
        if (mu == 0) {          // h0 = v0 + i v3 ; h1 = v1 + i v2
#pragma unroll
            for (int c = 0; c < 3; ++c) {
                hr[c]     = vr[c]     - vi[9 + c];  hi[c]     = vi[c]     + vr[9 + c];
                hr[3 + c] = vr[3 + c] - vi[6 + c];  hi[3 + c] = vi[3 + c] + vr[6 + c];
            }
        } else if (mu == 1) {   // h0 = v0 - v3 ; h1 = v1 + v2
#pragma unroll
            for (int c = 0; c < 3; ++c) {
                hr[c]     = vr[c]     - vr[9 + c];  hi[c]     = vi[c]     - vi[9 + c];
                hr[3 + c] = vr[3 + c] + vr[6 + c];  hi[3 + c] = vi[3 + c] + vi[6 + c];
            }
        } else if (mu == 2) {   // h0 = v0 + i v2 ; h1 = v1 - i v3
#pragma unroll
            for (int c = 0; c < 3; ++c) {
                hr[c]     = vr[c]     - vi[6 + c];  hi[c]     = vi[c]     + vr[6 + c];
                hr[3 + c] = vr[3 + c] + vi[9 + c];  hi[3 + c] = vi[3 + c] - vr[9 + c];
            }
        } else {                // h0 = v0 + v2 ; h1 = v1 + v3
#pragma unroll
            for (int c = 0; c < 3; ++c) {
                hr[c]     = vr[c]     + vr[6 + c];  hi[c]     = vi[c]     + vi[6 + c];
                hr[3 + c] = vr[3 + c] + vr[9 + c];  hi[3 + c] = vi[3 + c] + vi[9 + c];
            }
        }
        // g[s][i] = sum_j conj(U[j][i]) h[s][j]
#pragma unroll
        for (int s = 0; s < 2; ++s)
#pragma unroll
            for (int i = 0; i < 3; ++i) {
                float rr = 0.f, im = 0.f;
#pragma unroll
                for (int j = 0; j < 3; ++j) {
                    rr += ur[j * 3 + i] * hr[s * 3 + j] + ui[j * 3 + i] * hi[s * 3 + j];
                    im += ur[j * 3 + i] * hi[s * 3 + j] - ui[j * 3 + i] * hr[s * 3 + j];
                }
                gr[s * 3 + i] = rr; gi[s * 3 + i] = im;
            }
#pragma unroll
        for (int c = 0; c < 3; ++c) {
            ar[c]     += gr[c];      ai[c]     += gi[c];
            ar[3 + c] += gr[3 + c];  ai[3 + c] += gi[3 + c];
        }
        if (mu == 0) {          // r2 += -i g1 ; r3 += -i g0
#pragma unroll
            for (int c = 0; c < 3; ++c) {
                ar[6 + c] += gi[3 + c];  ai[6 + c] -= gr[3 + c];
                ar[9 + c] += gi[c];      ai[9 + c] -= gr[c];
            }
        } else if (mu == 1) {   // r2 += g1 ; r3 += -g0
#pragma unroll
            for (int c = 0; c < 3; ++c) {
                ar[6 + c] += gr[3 + c];  ai[6 + c] += gi[3 + c];
                ar[9 + c] -= gr[c];      ai[9 + c] -= gi[c];
            }
        } else if (mu == 2) {   // r2 += -i g0 ; r3 += i g1
#pragma unroll
            for (int c = 0; c < 3; ++c) {
                ar[6 + c] += gi[c];      ai[6 + c] -= gr[c];
                ar[9 + c] -= gi[3 + c];  ai[9 + c] += gr[3 + c];
            }
        } else {                // r2 += g0 ; r3 += g1
#pragma unroll
            for (int c = 0; c < 3; ++c) {
                ar[6 + c] += gr[c];      ai[6 + c] += gi[c];
                ar[9 + c] += gr[3 + c];  ai[9 + c] += gi[3 + c];
            }
        }
    }

    // out = -0.5 * acc, vectorized stores
    float4* orp = reinterpret_cast<float4*>(out_re + (size_t)site * 12);
    float4* oip = reinterpret_cast<float4*>(out_im + (size_t)site * 12);
    orp[0] = make_float4(-0.5f * ar[0], -0.5f * ar[1], -0.5f * ar[2],  -0.5f * ar[3]);
    orp[1] = make_float4(-0.5f * ar[4], -0.5f * ar[5], -0.5f * ar[6],  -0.5f * ar[7]);
    orp[2] = make_float4(-0.5f * ar[8], -0.5f * ar[9], -0.5f * ar[10], -0.5f * ar[11]);
    oip[0] = make_float4(-0.5f * ai[0], -0.5f * ai[1], -0.5f * ai[2],  -0.5f * ai[3]);
    oip[1] = make_float4(-0.5f * ai[4], -0.5f * ai[5], -0.5f * ai[6],  -0.5f * ai[7]);
    oip[2] = make_float4(-0.5f * ai[8], -0.5f * ai[9], -0.5f * ai[10], -0.5f * ai[11]);
}

extern "C" void kernel_launch(void* const* d_in, const int* in_sizes, int n_in,
                              void* d_out, int out_size, void* d_ws, size_t ws_size,
                              hipStream_t stream) {
    const float* psi_re = (const float*)d_in[0];
    const float* psi_im = (const float*)d_in[1];
    const float* U_re   = (const float*)d_in[2];
    const float* U_im   = (const float*)d_in[3];
    // d_in[4..7] are the projector matrices; hardcoded in-kernel.
    float* out_re = (float*)d_out;
    float* out_im = out_re + (size_t)SITES * 12;

    wilson_dslash_kernel<<<SITES / 128, 128, 0, stream>>>(
        psi_re, psi_im, U_re, U_im, out_re, out_im);
}

// Round 4
// 486.013 us; speedup vs baseline: 2.9392x; 1.1070x over previous
//
#include <hip/hip_runtime.h>

// Wilson Dslash, 32^4 lattice, DeGrand-Rossi basis, separate re/im fp32 planes.
// res(x) = -0.5 * sum_mu [ (I-g_mu) U_mu(x) psi(x+mu) + (I+g_mu) U_mu(x-mu)^dag psi(x-mu) ]
// Spin-projection trick: project to 2 half-spinors, color-multiply only those,
// reconstruct lower spin rows with fixed per-mu phases.
//
// R3 (kept): per-thread LDS staging of the full forward-U record (one contiguous
// fetch per record; runtime-mu chunk reads from LDS). FETCH 1.26->0.82 GB, 281us.
// R4: the remaining ~420MB overfetch is psi x/y-halo + backward-U(x-1,y-1) re-reads
// -- a block MAPPING problem (x-neighbors were 256 blocks apart, y-neighbors 8).
// Remap: block=(x, y, zq) tile of (z=4,t=32)=128 sites; XCD c owns the (x,y) patch
// [16*(c&1),+16) x [8*(c>>1),+8), zq fastest in dispatch order -> all x/y/z
// neighbor blocks of a patch-interior site share that XCD's 4MB L2.
// Compute body is byte-identical to R3: pure locality A/B.

static constexpr int SITES = 32 * 32 * 32 * 32;

__device__ __forceinline__ void load12(const float* __restrict__ p, float* v) {
    const float4* q = reinterpret_cast<const float4*>(p);  // site*12 floats = 48B, 16B-aligned
    float4 a = q[0], b = q[1], c = q[2];
    v[0] = a.x; v[1] = a.y; v[2]  = a.z; v[3]  = a.w;
    v[4] = b.x; v[5] = b.y; v[6]  = b.z; v[7]  = b.w;
    v[8] = c.x; v[9] = c.y; v[10] = c.z; v[11] = c.w;
}

__global__ __launch_bounds__(128) void wilson_dslash_kernel(
    const float* __restrict__ psi_re, const float* __restrict__ psi_im,
    const float* __restrict__ U_re,   const float* __restrict__ U_im,
    float* __restrict__ out_re,       float* __restrict__ out_im)
{
    // 8192 blocks = 8 XCDs x 1024. XCD c = blockIdx&7 gets a 16x8 (x,y) patch;
    // within the patch: zq fastest, then y, then x (nearby dispatch = nearby space).
    const int c   = blockIdx.x & 7;
    const int r   = blockIdx.x >> 3;      // [0,1024)
    const int xl  = r >> 6;               // [0,16)
    const int rem = r & 63;
    const int yl  = rem >> 3;             // [0,8)
    const int zq  = rem & 7;              // [0,8)
    const int x   = ((c & 1) << 4) | xl;
    const int y   = ((c >> 1) << 3) | yl;
    const int tid = threadIdx.x;
    const int site = (x << 15) | (y << 10) | (zq << 7) | tid;  // z = zq*4 + tid/32, t = tid%32

    // Per-thread LDS slot: [re 36][pad 4][im 36] dwords, stride 76 (304B, 16B-aligned).
    __shared__ float uf[128 * 76];
    float* myu = &uf[tid * 76];
    {
        const float4* pr = reinterpret_cast<const float4*>(U_re + (size_t)site * 36);
        const float4* pi = reinterpret_cast<const float4*>(U_im + (size_t)site * 36);
        float4* dr = reinterpret_cast<float4*>(myu);        // tid*304B, 16B-aligned
        float4* di = reinterpret_cast<float4*>(myu + 40);   // +160B, 16B-aligned
#pragma unroll
        for (int k = 0; k < 9; ++k) { dr[k] = pr[k]; di[k] = pi[k]; }
    }

    float ar[12], ai[12];   // accumulator, index = spin*3 + color
#pragma unroll
    for (int k = 0; k < 12; ++k) { ar[k] = 0.f; ai[k] = 0.f; }

#pragma unroll 1
    for (int mu = 0; mu < 4; ++mu) {
        const int sh  = 15 - 5 * mu;          // stride = 2^sh: x=15, y=10, z=5, t=0
        const int S   = 1 << sh;
        const int cmu = (site >> sh) & 31;
        const int nf  = site + (cmu == 31 ? -31 * S : S);   // x + mu (periodic)
        const int nb  = site + (cmu == 0  ?  31 * S : -S);  // x - mu (periodic)

        float vr[12], vi[12];
        float hr[6], hi[6];   // half-spinor, index = s*3 + color
        float gr[6], gi[6];

        // ================= forward hop: (I - g_mu) U_mu(x) psi(x+mu) =================
        load12(psi_re + (size_t)nf * 12, vr);
        load12(psi_im + (size_t)nf * 12, vi);
        const float* urp = myu + mu * 9;        // LDS, dynamic mu index OK
        const float* uip = myu + 40 + mu * 9;
        if (mu == 0) {          // h0 = v0 - i v3 ; h1 = v1 - i v2
#pragma unroll
            for (int c2 = 0; c2 < 3; ++c2) {
                hr[c2]     = vr[c2]     + vi[9 + c2];  hi[c2]     = vi[c2]     - vr[9 + c2];
                hr[3 + c2] = vr[3 + c2] + vi[6 + c2];  hi[3 + c2] = vi[3 + c2] - vr[6 + c2];
            }
        } else if (mu == 1) {   // h0 = v0 + v3 ; h1 = v1 - v2
#pragma unroll
            for (int c2 = 0; c2 < 3; ++c2) {
                hr[c2]     = vr[c2]     + vr[9 + c2];  hi[c2]     = vi[c2]     + vi[9 + c2];
                hr[3 + c2] = vr[3 + c2] - vr[6 + c2];  hi[3 + c2] = vi[3 + c2] - vi[6 + c2];
            }
        } else if (mu == 2) {   // h0 = v0 - i v2 ; h1 = v1 + i v3
#pragma unroll
            for (int c2 = 0; c2 < 3; ++c2) {
                hr[c2]     = vr[c2]     + vi[6 + c2];  hi[c2]     = vi[c2]     - vr[6 + c2];
                hr[3 + c2] = vr[3 + c2] - vi[9 + c2];  hi[3 + c2] = vi[3 + c2] + vr[9 + c2];
            }
        } else {                // h0 = v0 - v2 ; h1 = v1 - v3
#pragma unroll
            for (int c2 = 0; c2 < 3; ++c2) {
                hr[c2]     = vr[c2]     - vr[6 + c2];  hi[c2]     = vi[c2]     - vi[6 + c2];
                hr[3 + c2] = vr[3 + c2] - vr[9 + c2];  hi[3 + c2] = vi[3 + c2] - vi[9 + c2];
            }
        }
        // g[s][i] = sum_j U[i][j] h[s][j]   (complex), U from LDS
#pragma unroll
        for (int s = 0; s < 2; ++s)
#pragma unroll
            for (int i = 0; i < 3; ++i) {
                float rr = 0.f, im = 0.f;
#pragma unroll
                for (int j = 0; j < 3; ++j) {
                    const float a = urp[i * 3 + j], b = uip[i * 3 + j];
                    rr += a * hr[s * 3 + j] - b * hi[s * 3 + j];
                    im += a * hi[s * 3 + j] + b * hr[s * 3 + j];
                }
                gr[s * 3 + i] = rr; gi[s * 3 + i] = im;
            }
        // reconstruct: rows 0,1 += g0,g1 always; rows 2,3 per mu
#pragma unroll
        for (int c2 = 0; c2 < 3; ++c2) {
            ar[c2]     += gr[c2];      ai[c2]     += gi[c2];
            ar[3 + c2] += gr[3 + c2];  ai[3 + c2] += gi[3 + c2];
        }
        if (mu == 0) {          // r2 += i g1 ; r3 += i g0
#pragma unroll
            for (int c2 = 0; c2 < 3; ++c2) {
                ar[6 + c2] -= gi[3 + c2];  ai[6 + c2] += gr[3 + c2];
                ar[9 + c2] -= gi[c2];      ai[9 + c2] += gr[c2];
            }
        } else if (mu == 1) {   // r2 += -g1 ; r3 += g0
#pragma unroll
            for (int c2 = 0; c2 < 3; ++c2) {
                ar[6 + c2] -= gr[3 + c2];  ai[6 + c2] -= gi[3 + c2];
                ar[9 + c2] += gr[c2];      ai[9 + c2] += gi[c2];
            }
        } else if (mu == 2) {   // r2 += i g0 ; r3 += -i g1
#pragma unroll
            for (int c2 = 0; c2 < 3; ++c2) {
                ar[6 + c2] -= gi[c2];      ai[6 + c2] += gr[c2];
                ar[9 + c2] += gi[3 + c2];  ai[9 + c2] -= gr[3 + c2];
            }
        } else {                // r2 += -g0 ; r3 += -g1
#pragma unroll
            for (int c2 = 0; c2 < 3; ++c2) {
                ar[6 + c2] -= gr[c2];      ai[6 + c2] -= gi[c2];
                ar[9 + c2] -= gr[3 + c2];  ai[9 + c2] -= gi[3 + c2];
            }
        }

        // ================= backward hop: (I + g_mu) U_mu(x-mu)^dag psi(x-mu) =================
        load12(psi_re + (size_t)nb * 12, vr);
        load12(psi_im + (size_t)nb * 12, vi);
        float ur[9], ui[9];
        {
            // Aliases a neighbor block's staged record -> L2 (same XCD patch) / L3.
            const float* pur = U_re + ((size_t)nb * 4 + mu) * 9;
            const float* pui = U_im + ((size_t)nb * 4 + mu) * 9;
#pragma unroll
            for (int k = 0; k < 9; ++k) { ur[k] = pur[k]; ui[k] = pui[k]; }
        }
        if (mu == 0) {          // h0 = v0 + i v3 ; h1 = v1 + i v2
#pragma unroll
            for (int c2 = 0; c2 < 3; ++c2) {
                hr[c2]     = vr[c2]     - vi[9 + c2];  hi[c2]     = vi[c2]     + vr[9 + c2];
                hr[3 + c2] = vr[3 + c2] - vi[6 + c2];  hi[3 + c2] = vi[3 + c2] + vr[6 + c2];
            }
        } else if (mu == 1) {   // h0 = v0 - v3 ; h1 = v1 + v2
#pragma unroll
            for (int c2 = 0; c2 < 3; ++c2) {
                hr[c2]     = vr[c2]     - vr[9 + c2];  hi[c2]     = vi[c2]     - vi[9 + c2];
                hr[3 + c2] = vr[3 + c2] + vr[6 + c2];  hi[3 + c2] = vi[3 + c2] + vi[6 + c2];
            }
        } else if (mu == 2) {   // h0 = v0 + i v2 ; h1 = v1 - i v3
#pragma unroll
            for (int c2 = 0; c2 < 3; ++c2) {
                hr[c2]     = vr[c2]     - vi[6 + c2];  hi[c2]     = vi[c2]     + vr[6 + c2];
                hr[3 + c2] = vr[3 + c2] + vi[9 + c2];  hi[3 + c2] = vi[3 + c2] - vr[9 + c2];
            }
        } else {                // h0 = v0 + v2 ; h1 = v1 + v3
#pragma unroll
            for (int c2 = 0; c2 < 3; ++c2) {
                hr[c2]     = vr[c2]     + vr[6 + c2];  hi[c2]     = vi[c2]     + vi[6 + c2];
                hr[3 + c2] = vr[3 + c2] + vr[9 + c2];  hi[3 + c2] = vi[3 + c2] + vi[9 + c2];
            }
        }
        // g[s][i] = sum_j conj(U[j][i]) h[s][j]
#pragma unroll
        for (int s = 0; s < 2; ++s)
#pragma unroll
            for (int i = 0; i < 3; ++i) {
                float rr = 0.f, im = 0.f;
#pragma unroll
                for (int j = 0; j < 3; ++j) {
                    rr += ur[j * 3 + i] * hr[s * 3 + j] + ui[j * 3 + i] * hi[s * 3 + j];
                    im += ur[j * 3 + i] * hi[s * 3 + j] - ui[j * 3 + i] * hr[s * 3 + j];
                }
                gr[s * 3 + i] = rr; gi[s * 3 + i] = im;
            }
#pragma unroll
        for (int c2 = 0; c2 < 3; ++c2) {
            ar[c2]     += gr[c2];      ai[c2]     += gi[c2];
            ar[3 + c2] += gr[3 + c2];  ai[3 + c2] += gi[3 + c2];
        }
        if (mu == 0) {          // r2 += -i g1 ; r3 += -i g0
#pragma unroll
            for (int c2 = 0; c2 < 3; ++c2) {
                ar[6 + c2] += gi[3 + c2];  ai[6 + c2] -= gr[3 + c2];
                ar[9 + c2] += gi[c2];      ai[9 + c2] -= gr[c2];
            }
        } else if (mu == 1) {   // r2 += g1 ; r3 += -g0
#pragma unroll
            for (int c2 = 0; c2 < 3; ++c2) {
                ar[6 + c2] += gr[3 + c2];  ai[6 + c2] += gi[3 + c2];
                ar[9 + c2] -= gr[c2];      ai[9 + c2] -= gi[c2];
            }
        } else if (mu == 2) {   // r2 += -i g0 ; r3 += i g1
#pragma unroll
            for (int c2 = 0; c2 < 3; ++c2) {
                ar[6 + c2] += gi[c2];      ai[6 + c2] -= gr[c2];
                ar[9 + c2] -= gi[3 + c2];  ai[9 + c2] += gr[3 + c2];
            }
        } else {                // r2 += g0 ; r3 += g1
#pragma unroll
            for (int c2 = 0; c2 < 3; ++c2) {
                ar[6 + c2] += gr[c2];      ai[6 + c2] += gi[c2];
                ar[9 + c2] += gr[3 + c2];  ai[9 + c2] += gi[3 + c2];
            }
        }
    }

    // out = -0.5 * acc, vectorized stores (sites contiguous within a block)
    float4* orp = reinterpret_cast<float4*>(out_re + (size_t)site * 12);
    float4* oip = reinterpret_cast<float4*>(out_im + (size_t)site * 12);
    orp[0] = make_float4(-0.5f * ar[0], -0.5f * ar[1], -0.5f * ar[2],  -0.5f * ar[3]);
    orp[1] = make_float4(-0.5f * ar[4], -0.5f * ar[5], -0.5f * ar[6],  -0.5f * ar[7]);
    orp[2] = make_float4(-0.5f * ar[8], -0.5f * ar[9], -0.5f * ar[10], -0.5f * ar[11]);
    oip[0] = make_float4(-0.5f * ai[0], -0.5f * ai[1], -0.5f * ai[2],  -0.5f * ai[3]);
    oip[1] = make_float4(-0.5f * ai[4], -0.5f * ai[5], -0.5f * ai[6],  -0.5f * ai[7]);
    oip[2] = make_float4(-0.5f * ai[8], -0.5f * ai[9], -0.5f * ai[10], -0.5f * ai[11]);
}

extern "C" void kernel_launch(void* const* d_in, const int* in_sizes, int n_in,
                              void* d_out, int out_size, void* d_ws, size_t ws_size,
                              hipStream_t stream) {
    const float* psi_re = (const float*)d_in[0];
    const float* psi_im = (const float*)d_in[1];
    const float* U_re   = (const float*)d_in[2];
    const float* U_im   = (const float*)d_in[3];
    // d_in[4..7] are the projector matrices; hardcoded in-kernel.
    float* out_re = (float*)d_out;
    float* out_im = out_re + (size_t)SITES * 12;

    wilson_dslash_kernel<<<SITES / 128, 128, 0, stream>>>(
        psi_re, psi_im, U_re, U_im, out_re, out_im);
}